// Round 4
// baseline (107.685 us; speedup 1.0000x reference)
//
#include <hip/hip_runtime.h>
#include <math.h>

#define DIM 2048
#define NB 32
#define NK 256

typedef float vf4 __attribute__((ext_vector_type(4)));  // native vec4 (nontemporal-compatible)

// ---------------- Kernel A: Bsum[b,i] = sum_j |s[b,i] - s[b,j]| ----------------
// grid (8, 32): x = i-chunk of 256, y = batch. 256 threads, one i per thread.
// The j-values are wave-uniform (loop-counter index, uniform base pointer) ->
// compiler emits scalar s_load_dwordx* on the SMEM pipe; the VALU pipe is the
// only vector pipe in play: 2 VALU ops per |diff| (v_sub + v_add with abs
// modifier), 4 independent accumulator chains for latency hiding.
__global__ __launch_bounds__(256) void bsum_kernel(const float* __restrict__ scores,
                                                   float* __restrict__ bsum) {
    const int b = blockIdx.y;
    const int i = blockIdx.x * 256 + threadIdx.x;
    const float* __restrict__ row = scores + b * DIM;
    const float xi = row[i];

    float a0 = 0.f, a1 = 0.f, a2 = 0.f, a3 = 0.f;
    #pragma unroll 8
    for (int j = 0; j < DIM; j += 4) {
        a0 += fabsf(xi - row[j + 0]);   // row[j+*] is wave-uniform -> s_load
        a1 += fabsf(xi - row[j + 1]);
        a2 += fabsf(xi - row[j + 2]);
        a3 += fabsf(xi - row[j + 3]);
    }
    bsum[b * DIM + i] = (a0 + a1) + (a2 + a3);
}

// ---------------- Kernel B: row softmax over i for each (b,k) ----------------
// grid (NK/4, NB), 256 threads = 4 waves; each wave owns ONE k entirely:
// no barriers, no LDS, no cross-k register liveness (peak VGPR ~ e[32]+misc).
// Pure 6-step shuffle butterflies for max and sum. Nontemporal vf4 stores
// (output is never re-read; skip L2 allocation).
__global__ __launch_bounds__(256) void softmax_kernel(const float* __restrict__ scores,
                                                      const float* __restrict__ bsum,
                                                      float* __restrict__ out) {
    const int b = blockIdx.y;
    const int w = threadIdx.x >> 6;       // wave id within block
    const int t = threadIdx.x & 63;       // lane
    const int k = blockIdx.x * 4 + w;
    const float scale = (float)(DIM - 1 - 2 * k);  // 2047 - 2k

    const vf4* __restrict__ s4  = (const vf4*)(scores + b * DIM);
    const vf4* __restrict__ bs4 = (const vf4*)(bsum   + b * DIM);

    float e[32];
    #pragma unroll
    for (int q = 0; q < 8; ++q) {
        const vf4 sv = s4[t + 64 * q];    // 64 lanes x 16 B contiguous
        const vf4 bv = bs4[t + 64 * q];
        e[4 * q + 0] = fmaf(sv.x, scale, -bv.x);
        e[4 * q + 1] = fmaf(sv.y, scale, -bv.y);
        e[4 * q + 2] = fmaf(sv.z, scale, -bv.z);
        e[4 * q + 3] = fmaf(sv.w, scale, -bv.w);
    }

    // ---- wave max: 4 local chains then 6-step butterfly ----
    float m0 = e[0], m1 = e[1], m2 = e[2], m3 = e[3];
    #pragma unroll
    for (int j = 4; j < 32; j += 4) {
        m0 = fmaxf(m0, e[j + 0]);
        m1 = fmaxf(m1, e[j + 1]);
        m2 = fmaxf(m2, e[j + 2]);
        m3 = fmaxf(m3, e[j + 3]);
    }
    float m = fmaxf(fmaxf(m0, m1), fmaxf(m2, m3));
    #pragma unroll
    for (int off = 32; off > 0; off >>= 1) m = fmaxf(m, __shfl_xor(m, off, 64));

    // ---- exp + wave sum ----
    float s0 = 0.f, s1 = 0.f, s2 = 0.f, s3 = 0.f;
    #pragma unroll
    for (int j = 0; j < 32; j += 4) {
        e[j + 0] = __expf(e[j + 0] - m); s0 += e[j + 0];
        e[j + 1] = __expf(e[j + 1] - m); s1 += e[j + 1];
        e[j + 2] = __expf(e[j + 2] - m); s2 += e[j + 2];
        e[j + 3] = __expf(e[j + 3] - m); s3 += e[j + 3];
    }
    float s = (s0 + s1) + (s2 + s3);
    #pragma unroll
    for (int off = 32; off > 0; off >>= 1) s += __shfl_xor(s, off, 64);

    const float inv = 1.f / s;
    vf4* o4 = (vf4*)(out + ((size_t)(b * NK + k)) * DIM);
    #pragma unroll
    for (int q = 0; q < 8; ++q) {
        vf4 o;
        o.x = e[4 * q + 0] * inv;
        o.y = e[4 * q + 1] * inv;
        o.z = e[4 * q + 2] * inv;
        o.w = e[4 * q + 3] * inv;
        __builtin_nontemporal_store(o, &o4[t + 64 * q]);
    }
}

extern "C" void kernel_launch(void* const* d_in, const int* in_sizes, int n_in,
                              void* d_out, int out_size, void* d_ws, size_t ws_size,
                              hipStream_t stream) {
    const float* scores = (const float*)d_in[0];
    float* out  = (float*)d_out;
    float* bsum = (float*)d_ws;  // NB*DIM floats = 256 KiB

    bsum_kernel<<<dim3(8, NB), 256, 0, stream>>>(scores, bsum);
    softmax_kernel<<<dim3(NK / 4, NB), 256, 0, stream>>>(scores, bsum, out);
}

// Round 5
// 91.855 us; speedup vs baseline: 1.1723x; 1.1723x over previous
//
#include <hip/hip_runtime.h>
#include <math.h>

#define DIM 2048
#define NB 32
#define NK 256

typedef float vf4 __attribute__((ext_vector_type(4)));

// ---------------- Kernel A: Bsum[b,i] = sum_j |s[b,i] - s[b,j]| ----------------
// grid (2, 4, 32): x = i-chunk (1024 i), y = j-chunk (512 j), z = batch.
// 256 threads, 4 consecutive i per thread. j-chunk staged in LDS (2 KiB);
// inner loop reads LDS float4 broadcasts (wave-uniform -> conflict-free).
// Per thread: 128 ds_read_b128 + 4096 VALU ops -> VALU-bound (~3.4 us floor).
// Partials merged with atomicAdd after memset.
__global__ __launch_bounds__(256) void bsum_kernel(const float* __restrict__ scores,
                                                   float* __restrict__ bsum) {
    __shared__ vf4 srow[128];  // 512 floats = 2 KiB
    const int b  = blockIdx.z;
    const int j0 = blockIdx.y * 512;
    const int i0 = blockIdx.x * 1024;
    const float* __restrict__ row = scores + b * DIM;

    if (threadIdx.x < 128) srow[threadIdx.x] = ((const vf4*)(row + j0))[threadIdx.x];
    __syncthreads();

    const vf4 xi = ((const vf4*)(row + i0))[threadIdx.x];
    float a0 = 0.f, a1 = 0.f, a2 = 0.f, a3 = 0.f;
    #pragma unroll 4
    for (int jj = 0; jj < 128; ++jj) {
        const vf4 xj = srow[jj];
        a0 += (fabsf(xi.x - xj.x) + fabsf(xi.x - xj.y)) + (fabsf(xi.x - xj.z) + fabsf(xi.x - xj.w));
        a1 += (fabsf(xi.y - xj.x) + fabsf(xi.y - xj.y)) + (fabsf(xi.y - xj.z) + fabsf(xi.y - xj.w));
        a2 += (fabsf(xi.z - xj.x) + fabsf(xi.z - xj.y)) + (fabsf(xi.z - xj.z) + fabsf(xi.z - xj.w));
        a3 += (fabsf(xi.w - xj.x) + fabsf(xi.w - xj.y)) + (fabsf(xi.w - xj.z) + fabsf(xi.w - xj.w));
    }
    float* dst = bsum + b * DIM + i0 + threadIdx.x * 4;
    atomicAdd(dst + 0, a0);
    atomicAdd(dst + 1, a1);
    atomicAdd(dst + 2, a2);
    atomicAdd(dst + 3, a3);
}

// ---------------- Kernel B: row softmax over i for each (b,k) ----------------
// grid (NK/4, NB), 256 threads = 4 waves; each wave owns ONE k entirely:
// no barriers, no LDS, no cross-k register liveness. Pure 6-step shuffle
// butterflies. Plain (cached) float4 stores — nt regressed in round 4.
__global__ __launch_bounds__(256) void softmax_kernel(const float* __restrict__ scores,
                                                      const float* __restrict__ bsum,
                                                      float* __restrict__ out) {
    const int b = blockIdx.y;
    const int w = threadIdx.x >> 6;       // wave id within block
    const int t = threadIdx.x & 63;       // lane
    const int k = blockIdx.x * 4 + w;
    const float scale = (float)(DIM - 1 - 2 * k);  // 2047 - 2k

    const vf4* __restrict__ s4  = (const vf4*)(scores + b * DIM);
    const vf4* __restrict__ bs4 = (const vf4*)(bsum   + b * DIM);

    float e[32];
    #pragma unroll
    for (int q = 0; q < 8; ++q) {
        const vf4 sv = s4[t + 64 * q];    // 64 lanes x 16 B contiguous
        const vf4 bv = bs4[t + 64 * q];
        e[4 * q + 0] = fmaf(sv.x, scale, -bv.x);
        e[4 * q + 1] = fmaf(sv.y, scale, -bv.y);
        e[4 * q + 2] = fmaf(sv.z, scale, -bv.z);
        e[4 * q + 3] = fmaf(sv.w, scale, -bv.w);
    }

    // ---- wave max: 4 local chains then 6-step butterfly ----
    float m0 = e[0], m1 = e[1], m2 = e[2], m3 = e[3];
    #pragma unroll
    for (int j = 4; j < 32; j += 4) {
        m0 = fmaxf(m0, e[j + 0]);
        m1 = fmaxf(m1, e[j + 1]);
        m2 = fmaxf(m2, e[j + 2]);
        m3 = fmaxf(m3, e[j + 3]);
    }
    float m = fmaxf(fmaxf(m0, m1), fmaxf(m2, m3));
    #pragma unroll
    for (int off = 32; off > 0; off >>= 1) m = fmaxf(m, __shfl_xor(m, off, 64));

    // ---- exp + wave sum ----
    float s0 = 0.f, s1 = 0.f, s2 = 0.f, s3 = 0.f;
    #pragma unroll
    for (int j = 0; j < 32; j += 4) {
        e[j + 0] = __expf(e[j + 0] - m); s0 += e[j + 0];
        e[j + 1] = __expf(e[j + 1] - m); s1 += e[j + 1];
        e[j + 2] = __expf(e[j + 2] - m); s2 += e[j + 2];
        e[j + 3] = __expf(e[j + 3] - m); s3 += e[j + 3];
    }
    float s = (s0 + s1) + (s2 + s3);
    #pragma unroll
    for (int off = 32; off > 0; off >>= 1) s += __shfl_xor(s, off, 64);

    const float inv = 1.f / s;
    vf4* o4 = (vf4*)(out + ((size_t)(b * NK + k)) * DIM);
    #pragma unroll
    for (int q = 0; q < 8; ++q) {
        vf4 o;
        o.x = e[4 * q + 0] * inv;
        o.y = e[4 * q + 1] * inv;
        o.z = e[4 * q + 2] * inv;
        o.w = e[4 * q + 3] * inv;
        o4[t + 64 * q] = o;
    }
}

extern "C" void kernel_launch(void* const* d_in, const int* in_sizes, int n_in,
                              void* d_out, int out_size, void* d_ws, size_t ws_size,
                              hipStream_t stream) {
    const float* scores = (const float*)d_in[0];
    float* out  = (float*)d_out;
    float* bsum = (float*)d_ws;  // NB*DIM floats = 256 KiB

    hipMemsetAsync(bsum, 0, (size_t)NB * DIM * sizeof(float), stream);
    bsum_kernel<<<dim3(2, 4, NB), 256, 0, stream>>>(scores, bsum);
    softmax_kernel<<<dim3(NK / 4, NB), 256, 0, stream>>>(scores, bsum, out);
}